// Round 3
// baseline (580.481 us; speedup 1.0000x reference)
//
#include <hip/hip_runtime.h>
#include <math.h>

// Dynamic routing (capsule nets): B=128, J=32, I=1152, N=16, iters=3, topk=[0.3,0.3]
//
// Pipeline (all fp32, 3 full streams over the 302MB u_hat):
//   memset(s1,s2,ent)                     -- atomically-accumulated buffers
//   P1: s0[b,j,n] = (1/32) sum_i u        -- pure reduction (c0 uniform)
//   V : v0 = squash(s0 + bias)
//   P2: per column: a0=U.v0 -> kth0 -> mask -> c1 -> ent1, s1 += c1*U
//   V : v1 = squash(s1 + bias)
//   P3: a0 recomputed (bit-identical), a1=U.v1, b2=mask(a0)+a1 -> c2 -> ent2, s2
//   V2: d_out = squash(s2+bias), stats[3]
//
// sparsify at iter1 is a provable no-op (9 entries already -inf -> kth=-inf),
// so only kth0 per column is persisted, not b_vec.

#define NB 128
#define NJ 32
#define NI 1152
#define NN 16
#define TI 32
#define NTILES (NI / TI)          // 36
#define COLS_TOTAL (NB * NI)      // 147456

// ---------------------------------------------------------------- P1: s0
__global__ __launch_bounds__(256) void k_reduce_s0(const float* __restrict__ u,
                                                   float* __restrict__ s0) {
  int bj = blockIdx.x;  // b*32 + j
  const float4* u4 = (const float4*)u + (size_t)bj * (NI * NN / 4);  // 4608 float4
  int t = threadIdx.x;
  float4 acc = make_float4(0.f, 0.f, 0.f, 0.f);
#pragma unroll
  for (int k = 0; k < 18; ++k) {
    float4 x = u4[t + 256 * k];
    acc.x += x.x; acc.y += x.y; acc.z += x.z; acc.w += x.w;
  }
  // reduce lanes sharing t%4 (same n-quad): xor over bits 2..5
#pragma unroll
  for (int m = 4; m <= 32; m <<= 1) {
    acc.x += __shfl_xor(acc.x, m);
    acc.y += __shfl_xor(acc.y, m);
    acc.z += __shfl_xor(acc.z, m);
    acc.w += __shfl_xor(acc.w, m);
  }
  __shared__ float4 parts[4][4];
  int lane = t & 63, w = t >> 6;
  if (lane < 4) parts[w][lane] = acc;
  __syncthreads();
  if (t < 4) {
    float4 p0 = parts[0][t], p1 = parts[1][t], p2 = parts[2][t], p3 = parts[3][t];
    float4 r;
    r.x = (p0.x + p1.x + p2.x + p3.x) * (1.0f / 32.0f);
    r.y = (p0.y + p1.y + p2.y + p3.y) * (1.0f / 32.0f);
    r.z = (p0.z + p1.z + p2.z + p3.z) * (1.0f / 32.0f);
    r.w = (p0.w + p1.w + p2.w + p3.w) * (1.0f / 32.0f);
    ((float4*)(s0 + (size_t)bj * NN))[t] = r;
  }
}

// ---------------------------------------------------------------- squash
__global__ __launch_bounds__(256) void k_squash(const float* __restrict__ s,
                                                const float* __restrict__ bias,
                                                float* __restrict__ vout,
                                                const float* __restrict__ ent,
                                                int write_stats) {
  int gid = blockIdx.x * 256 + threadIdx.x;   // [0, 65536)
  int vec = gid >> 4, n = gid & 15;
  int j = vec & 31;
  float sv = s[gid];
  float ssum = sv;
#pragma unroll
  for (int m = 1; m < 16; m <<= 1) ssum += __shfl_xor(ssum, m);
  float sb = sv + bias[j * NN + n];
  if (ssum == 0.0f) sb = 0.0f;  // reference reset_mask
  float sq = sb * sb;
#pragma unroll
  for (int m = 1; m < 16; m <<= 1) sq += __shfl_xor(sq, m);
  vout[gid] = (sq / (1.0f + sq)) * sb / sqrtf(sq);
  if (write_stats && gid < 3) {
    float val = (gid == 0) ? logf(32.0f) : ent[gid - 1] / (float)COLS_TOTAL;
    vout[NB * NJ * NN + gid] = val;
  }
}

// ---------------------------------------------------------------- routing pass
// SPARS=1: P2 (a0 from vA=v0, rank->kth0->mask, c1, s1)
// SPARS=0: P3 (a1 from vA=v1, a0 from vB=v0 recomputed, mask via kth0, c2, s2)
// LDS tile layout: chunk L(j,col,q) = (j/8)*1024 + q*256 + (j%8)*32 + col
//   -> phase-B float4 reads are per-wave contiguous (conflict-free).
template <int SPARS>
__global__ __launch_bounds__(256, 2) void k_route(const float* __restrict__ u,
                                                  const float* __restrict__ vprev,
                                                  const float* __restrict__ v0,
                                                  float* __restrict__ kth0,
                                                  float* __restrict__ s_out,
                                                  float* __restrict__ ent_accum) {
  __shared__ __align__(16) float U[16384];   // 64 KB tile
  __shared__ __align__(16) float vA[512];
  __shared__ __align__(16) float vB[512];
  __shared__ float bcols[32 * 37];           // [col][j], stride 37 (bank spread)
  __shared__ float ctile[32 * 37];
  __shared__ float entc[32];

  int t = threadIdx.x;
  int bid = blockIdx.x;
  int b = bid / NTILES;
  int tile = bid - b * NTILES;
  int i0 = tile * TI;
  const float4* ub4 = (const float4*)(u + (size_t)b * (NJ * NI * NN) + (size_t)i0 * NN);

  // ---- Phase A: stage tile (coalesced global float4, permuted LDS write)
#pragma unroll
  for (int m = 0; m < 16; ++m) {
    int g = m * 256 + t;                  // linear global chunk id: j*128 + col*4 + q
    int j = g >> 7;
    int L = ((j >> 3) << 10) + ((g & 3) << 8) + ((j & 7) << 5) + ((g >> 2) & 31);
    float4 x = ub4[g + j * 4480];         // = j*4608 + col*4 + q
    *(float4*)&U[4 * L] = x;
  }
  // v-vectors for THIS batch b (fix R1: was missing the b offset)
  {
    const float4* vprev4 = (const float4*)(vprev + (size_t)b * (NJ * NN));
    if (t < 128) ((float4*)vA)[t] = vprev4[t];
    if (SPARS == 0) {
      const float4* v04 = (const float4*)(v0 + (size_t)b * (NJ * NN));
      if (t >= 128) ((float4*)vB)[t - 128] = v04[t - 128];
    }
  }
  __syncthreads();

  // ---- Phase B: agreement dots; per thread: col=t%32, jg=t/32, j=8*q2+jg
  {
    int col = t & 31;
    int jg = t >> 5;
    float kthcol = 0.f;
    if (SPARS == 0) kthcol = kth0[b * NI + i0 + col];
#pragma unroll
    for (int q2 = 0; q2 < 4; ++q2) {
      int j = q2 * 8 + jg;
      float accA = 0.f, accB = 0.f;
#pragma unroll
      for (int q = 0; q < 4; ++q) {
        float4 uu = *(const float4*)&U[(q2 << 12) + (q << 10) + 4 * t];
        float4 va = *(const float4*)&vA[j * 16 + q * 4];
        accA = fmaf(uu.x, va.x, accA);
        accA = fmaf(uu.y, va.y, accA);
        accA = fmaf(uu.z, va.z, accA);
        accA = fmaf(uu.w, va.w, accA);
        if (SPARS == 0) {  // a0 recompute: SAME fmaf order as P2's accA -> bit-identical
          float4 vb = *(const float4*)&vB[j * 16 + q * 4];
          accB = fmaf(uu.x, vb.x, accB);
          accB = fmaf(uu.y, vb.y, accB);
          accB = fmaf(uu.z, vb.z, accB);
          accB = fmaf(uu.w, vb.w, accB);
        }
      }
      float bv;
      if (SPARS)
        bv = accA;  // b1_pre = 0 + a0
      else
        bv = ((accB <= kthcol) ? -INFINITY : accB) + accA;  // b2 = mask(a0) + a1
      bcols[col * 37 + j] = bv;
    }
  }
  __syncthreads();

  // ---- Phase S: per column (8 lanes/col): [rank->kth->mask], softmax, entropy
  {
    int col = t >> 3, sg = t & 7;
    float own0 = bcols[col * 37 + sg * 4 + 0];
    float own1 = bcols[col * 37 + sg * 4 + 1];
    float own2 = bcols[col * 37 + sg * 4 + 2];
    float own3 = bcols[col * 37 + sg * 4 + 3];
    float m;
    if (SPARS) {
      int r0 = 0, r1 = 0, r2 = 0, r3 = 0, e0 = 0, e1 = 0, e2 = 0, e3 = 0;
      m = -INFINITY;
#pragma unroll
      for (int jj = 0; jj < 32; ++jj) {
        float bj = bcols[col * 37 + jj];  // 8-lane broadcast
        m = fmaxf(m, bj);
        r0 += (bj < own0); e0 += (bj == own0);
        r1 += (bj < own1); e1 += (bj == own1);
        r2 += (bj < own2); e2 += (bj == own2);
        r3 += (bj < own3); e3 += (bj == own3);
      }
      // kth smallest (sorted index 8 == mask_count-1): r<=8 < r+eq
      float cand = -INFINITY;
      if (r0 <= 8 && 8 < r0 + e0) cand = fmaxf(cand, own0);
      if (r1 <= 8 && 8 < r1 + e1) cand = fmaxf(cand, own1);
      if (r2 <= 8 && 8 < r2 + e2) cand = fmaxf(cand, own2);
      if (r3 <= 8 && 8 < r3 + e3) cand = fmaxf(cand, own3);
      cand = fmaxf(cand, __shfl_xor(cand, 1));
      cand = fmaxf(cand, __shfl_xor(cand, 2));
      cand = fmaxf(cand, __shfl_xor(cand, 4));
      if (own0 <= cand) own0 = -INFINITY;
      if (own1 <= cand) own1 = -INFINITY;
      if (own2 <= cand) own2 = -INFINITY;
      if (own3 <= cand) own3 = -INFINITY;
      if (sg == 0) kth0[b * NI + i0 + col] = cand;
      // m (pre-mask max) == post-mask max: the max always survives masking
    } else {
      float lm = fmaxf(fmaxf(own0, own1), fmaxf(own2, own3));
      lm = fmaxf(lm, __shfl_xor(lm, 1));
      lm = fmaxf(lm, __shfl_xor(lm, 2));
      lm = fmaxf(lm, __shfl_xor(lm, 4));
      m = lm;
    }
    float x0 = expf(own0 - m), x1 = expf(own1 - m);
    float x2 = expf(own2 - m), x3 = expf(own3 - m);
    float ps = (x0 + x1) + (x2 + x3);
    ps += __shfl_xor(ps, 1);
    ps += __shfl_xor(ps, 2);
    ps += __shfl_xor(ps, 4);
    float c0 = x0 / ps, c1 = x1 / ps, c2 = x2 / ps, c3 = x3 / ps;
    ctile[col * 37 + sg * 4 + 0] = c0;
    ctile[col * 37 + sg * 4 + 1] = c1;
    ctile[col * 37 + sg * 4 + 2] = c2;
    ctile[col * 37 + sg * 4 + 3] = c3;
    float ent = 0.f;
    if (c0 > 0.f) ent += c0 * logf(c0);
    if (c1 > 0.f) ent += c1 * logf(c1);
    if (c2 > 0.f) ent += c2 * logf(c2);
    if (c3 > 0.f) ent += c3 * logf(c3);
    ent += __shfl_xor(ent, 1);
    ent += __shfl_xor(ent, 2);
    ent += __shfl_xor(ent, 4);
    if (sg == 0) entc[col] = -ent;
  }
  __syncthreads();

  // ---- Phase D: s[b,j,n] += sum_col c[col][j] * U[col][j][n]; (j,np) per thread
  {
    int j = t >> 3, np = t & 7;
    int q = np >> 1, half = np & 1;
    int jg = j & 7, q2 = j >> 3;
    const float* Ub = &U[(q2 << 12) + (q << 10) + (jg << 7) + 2 * half];
    int coff = (np + j) & 31;  // stagger for LDS bank spread
    float acc0 = 0.f, acc1 = 0.f;
#pragma unroll
    for (int cc = 0; cc < 32; ++cc) {
      int col = (cc + coff) & 31;
      float c = ctile[col * 37 + j];
      float2 uu = *(const float2*)&Ub[4 * col];
      acc0 = fmaf(c, uu.x, acc0);
      acc1 = fmaf(c, uu.y, acc1);
    }
    int outi = (b * NJ + j) * NN + 2 * np;
    unsafeAtomicAdd(&s_out[outi], acc0);
    unsafeAtomicAdd(&s_out[outi + 1], acc1);
  }
  // ---- block entropy flush (entc stable since pre-D barrier)
  if (t < 32) {
    float e = entc[t];
    e += __shfl_xor(e, 1);
    e += __shfl_xor(e, 2);
    e += __shfl_xor(e, 4);
    e += __shfl_xor(e, 8);
    e += __shfl_xor(e, 16);
    if (t == 0) unsafeAtomicAdd(ent_accum, e);
  }
}

// ---------------------------------------------------------------- launch
extern "C" void kernel_launch(void* const* d_in, const int* in_sizes, int n_in,
                              void* d_out, int out_size, void* d_ws, size_t ws_size,
                              hipStream_t stream) {
  (void)in_sizes; (void)n_in; (void)out_size; (void)ws_size;
  const float* u = (const float*)d_in[0];
  const float* bias = (const float*)d_in[1];
  float* ws = (float*)d_ws;
  // ws layout (floats): [s1 65536][s2 65536][ent 2 + pad 2][s0 65536][v0 65536][v1 65536][kth0 147456]
  float* s1 = ws;
  float* s2 = ws + 65536;
  float* ent = ws + 131072;
  float* s0 = ws + 131076;
  float* v0 = ws + 196612;
  float* v1 = ws + 262148;
  float* kth0 = ws + 327684;
  float* dout = (float*)d_out;

  hipMemsetAsync(d_ws, 0, (size_t)(131072 + 4) * sizeof(float), stream);  // s1,s2,ent

  k_reduce_s0<<<dim3(NB * NJ), dim3(256), 0, stream>>>(u, s0);
  k_squash<<<dim3(256), dim3(256), 0, stream>>>(s0, bias, v0, (const float*)nullptr, 0);
  k_route<1><<<dim3(NB * NTILES), dim3(256), 0, stream>>>(u, v0, (const float*)nullptr,
                                                          kth0, s1, ent + 0);
  k_squash<<<dim3(256), dim3(256), 0, stream>>>(s1, bias, v1, (const float*)nullptr, 0);
  k_route<0><<<dim3(NB * NTILES), dim3(256), 0, stream>>>(u, v1, v0, kth0, s2, ent + 1);
  k_squash<<<dim3(256), dim3(256), 0, stream>>>(s2, bias, dout, ent, 1);
}

// Round 4
// 573.090 us; speedup vs baseline: 1.0129x; 1.0129x over previous
//
#include <hip/hip_runtime.h>
#include <math.h>

// Dynamic routing (capsule nets): B=128, J=32, I=1152, N=16, iters=3, topk=[0.3,0.3]
//
// R4: register-resident U in k_route (no 64KB LDS tile, no staging barrier).
// Thread owns (j = t>>3, cols cg+8k, k=0..3) with all 16 n in 64 VGPRs.
//   Phase B: a[j,col] = U.v, v read straight from global (L1 broadcast).
//   Phase S: per-column softmax/rank over j via small LDS (bank-rotated).
//   Phase D: s[j,n] = sum_col c*U -> in-lane over 4 cols + 8-lane fold reduce.
// sparsify at iter1 is a provable no-op (9 entries already -inf -> kth=-inf),
// so only kth0 per column is persisted; P3 recomputes a0 bit-identically.

#define NB 128
#define NJ 32
#define NI 1152
#define NN 16
#define TI 32
#define NTILES (NI / TI)          // 36
#define COLS_TOTAL (NB * NI)      // 147456

// LDS address for (j,col) score/coeff tiles: stride 33 + col rotate by 4j.
// Bank = (5j + col) mod 32: column-direction reads (fixed col, j varies) are
// conflict-free; row-direction (fixed j, col=cg+8k) ~2-way.
__device__ __forceinline__ int bca(int j, int col) {
  return j * 33 + ((col + 4 * j) & 31);
}

// ---------------------------------------------------------------- P1: s0
__global__ __launch_bounds__(256) void k_reduce_s0(const float* __restrict__ u,
                                                   float* __restrict__ s0) {
  int bj = blockIdx.x;  // b*32 + j
  const float4* u4 = (const float4*)u + (size_t)bj * (NI * NN / 4);  // 4608 float4
  int t = threadIdx.x;
  float4 acc = make_float4(0.f, 0.f, 0.f, 0.f);
#pragma unroll
  for (int k = 0; k < 18; ++k) {
    float4 x = u4[t + 256 * k];
    acc.x += x.x; acc.y += x.y; acc.z += x.z; acc.w += x.w;
  }
#pragma unroll
  for (int m = 4; m <= 32; m <<= 1) {
    acc.x += __shfl_xor(acc.x, m);
    acc.y += __shfl_xor(acc.y, m);
    acc.z += __shfl_xor(acc.z, m);
    acc.w += __shfl_xor(acc.w, m);
  }
  __shared__ float4 parts[4][4];
  int lane = t & 63, w = t >> 6;
  if (lane < 4) parts[w][lane] = acc;
  __syncthreads();
  if (t < 4) {
    float4 p0 = parts[0][t], p1 = parts[1][t], p2 = parts[2][t], p3 = parts[3][t];
    float4 r;
    r.x = (p0.x + p1.x + p2.x + p3.x) * (1.0f / 32.0f);
    r.y = (p0.y + p1.y + p2.y + p3.y) * (1.0f / 32.0f);
    r.z = (p0.z + p1.z + p2.z + p3.z) * (1.0f / 32.0f);
    r.w = (p0.w + p1.w + p2.w + p3.w) * (1.0f / 32.0f);
    ((float4*)(s0 + (size_t)bj * NN))[t] = r;
  }
}

// ---------------------------------------------------------------- squash
__global__ __launch_bounds__(256) void k_squash(const float* __restrict__ s,
                                                const float* __restrict__ bias,
                                                float* __restrict__ vout,
                                                const float* __restrict__ ent,
                                                int write_stats) {
  int gid = blockIdx.x * 256 + threadIdx.x;   // [0, 65536)
  int n = gid & 15;
  int j = (gid >> 4) & 31;
  float sv = s[gid];
  float ssum = sv;
#pragma unroll
  for (int m = 1; m < 16; m <<= 1) ssum += __shfl_xor(ssum, m);
  float sb = sv + bias[j * NN + n];
  if (ssum == 0.0f) sb = 0.0f;  // reference reset_mask
  float sq = sb * sb;
#pragma unroll
  for (int m = 1; m < 16; m <<= 1) sq += __shfl_xor(sq, m);
  vout[gid] = (sq / (1.0f + sq)) * sb / sqrtf(sq);
  if (write_stats && gid < 3) {
    float val = (gid == 0) ? logf(32.0f) : ent[gid - 1] / (float)COLS_TOTAL;
    vout[NB * NJ * NN + gid] = val;
  }
}

// ---------------------------------------------------------------- routing pass
// SPARS=1: P2 (a0=U.v0, rank->kth0->mask, c1, ent1, s1)
// SPARS=0: P3 (a1=U.v1, a0 recomputed bit-identically from v0, mask via kth0,
//              c2, ent2, s2)
template <int SPARS>
__global__ __launch_bounds__(256) void k_route(const float* __restrict__ u,
                                               const float* __restrict__ vprev,
                                               const float* __restrict__ v0,
                                               float* __restrict__ kth0,
                                               float* __restrict__ s_out,
                                               float* __restrict__ ent_accum) {
  __shared__ float bc[32 * 33];   // scores,  bca layout
  __shared__ float ct[32 * 33];   // coeffs,  bca layout
  __shared__ float entc[32];

  int t = threadIdx.x;
  int bid = blockIdx.x;
  int b = bid / NTILES;
  int tile = bid - b * NTILES;
  int i0 = tile * TI;
  int j = t >> 3, cg = t & 7;

  // ---- U into registers: Ur[k][q] = u[b,j,i0+cg+8k, 4q..4q+3]
  const float4* up = (const float4*)u + ((size_t)(b * NJ + j) * NI + i0 + cg) * 4;
  float4 Ur[4][4];
#pragma unroll
  for (int k = 0; k < 4; ++k)
#pragma unroll
    for (int q = 0; q < 4; ++q) Ur[k][q] = up[k * 32 + q];

  // ---- Phase B: agreement dots (accA with vprev; accB recompute with v0)
  float kthc[4];
  if (SPARS == 0) {
#pragma unroll
    for (int k = 0; k < 4; ++k) kthc[k] = kth0[b * NI + i0 + cg + 8 * k];
  }
  const float4* vA4 = (const float4*)vprev + (b * NJ + j) * 4;
  const float4* vB4 = (const float4*)v0 + (b * NJ + j) * 4;
  float accA[4] = {0.f, 0.f, 0.f, 0.f};
  float accB[4] = {0.f, 0.f, 0.f, 0.f};
#pragma unroll
  for (int q = 0; q < 4; ++q) {
    float4 vaq = vA4[q];
    float4 vbq;
    if (SPARS == 0) vbq = vB4[q];
#pragma unroll
    for (int k = 0; k < 4; ++k) {
      float4 uu = Ur[k][q];
      accA[k] = fmaf(uu.x, vaq.x, accA[k]);
      accA[k] = fmaf(uu.y, vaq.y, accA[k]);
      accA[k] = fmaf(uu.z, vaq.z, accA[k]);
      accA[k] = fmaf(uu.w, vaq.w, accA[k]);
      if (SPARS == 0) {  // same fmaf order as P2's accA -> bit-identical a0
        accB[k] = fmaf(uu.x, vbq.x, accB[k]);
        accB[k] = fmaf(uu.y, vbq.y, accB[k]);
        accB[k] = fmaf(uu.z, vbq.z, accB[k]);
        accB[k] = fmaf(uu.w, vbq.w, accB[k]);
      }
    }
  }
#pragma unroll
  for (int k = 0; k < 4; ++k) {
    float bv;
    if (SPARS)
      bv = accA[k];  // b1_pre = 0 + a0
    else
      bv = ((accB[k] <= kthc[k]) ? -INFINITY : accB[k]) + accA[k];  // b2
    bc[bca(j, cg + 8 * k)] = bv;
  }
  __syncthreads();

  // ---- Phase S: per column (8 lanes/col): [rank->kth->mask], softmax, entropy
  {
    int col = t >> 3, sg = t & 7;
    float own0 = bc[bca(sg * 4 + 0, col)];
    float own1 = bc[bca(sg * 4 + 1, col)];
    float own2 = bc[bca(sg * 4 + 2, col)];
    float own3 = bc[bca(sg * 4 + 3, col)];
    float m;
    if (SPARS) {
      int r0 = 0, r1 = 0, r2 = 0, r3 = 0, e0 = 0, e1 = 0, e2 = 0, e3 = 0;
      m = -INFINITY;
#pragma unroll
      for (int jj = 0; jj < 32; ++jj) {
        float bj = bc[bca(jj, col)];  // 8-lane broadcast
        m = fmaxf(m, bj);
        r0 += (bj < own0); e0 += (bj == own0);
        r1 += (bj < own1); e1 += (bj == own1);
        r2 += (bj < own2); e2 += (bj == own2);
        r3 += (bj < own3); e3 += (bj == own3);
      }
      // kth smallest (sorted index 8 == mask_count-1): r<=8 < r+eq
      float cand = -INFINITY;
      if (r0 <= 8 && 8 < r0 + e0) cand = fmaxf(cand, own0);
      if (r1 <= 8 && 8 < r1 + e1) cand = fmaxf(cand, own1);
      if (r2 <= 8 && 8 < r2 + e2) cand = fmaxf(cand, own2);
      if (r3 <= 8 && 8 < r3 + e3) cand = fmaxf(cand, own3);
      cand = fmaxf(cand, __shfl_xor(cand, 1));
      cand = fmaxf(cand, __shfl_xor(cand, 2));
      cand = fmaxf(cand, __shfl_xor(cand, 4));
      if (own0 <= cand) own0 = -INFINITY;
      if (own1 <= cand) own1 = -INFINITY;
      if (own2 <= cand) own2 = -INFINITY;
      if (own3 <= cand) own3 = -INFINITY;
      if (sg == 0) kth0[b * NI + i0 + col] = cand;
      // pre-mask max == post-mask max: the max always survives masking
    } else {
      float lm = fmaxf(fmaxf(own0, own1), fmaxf(own2, own3));
      lm = fmaxf(lm, __shfl_xor(lm, 1));
      lm = fmaxf(lm, __shfl_xor(lm, 2));
      lm = fmaxf(lm, __shfl_xor(lm, 4));
      m = lm;
    }
    float x0 = expf(own0 - m), x1 = expf(own1 - m);
    float x2 = expf(own2 - m), x3 = expf(own3 - m);
    float ps = (x0 + x1) + (x2 + x3);
    ps += __shfl_xor(ps, 1);
    ps += __shfl_xor(ps, 2);
    ps += __shfl_xor(ps, 4);
    float c0 = x0 / ps, c1 = x1 / ps, c2 = x2 / ps, c3 = x3 / ps;
    ct[bca(sg * 4 + 0, col)] = c0;
    ct[bca(sg * 4 + 1, col)] = c1;
    ct[bca(sg * 4 + 2, col)] = c2;
    ct[bca(sg * 4 + 3, col)] = c3;
    float ent = 0.f;
    if (c0 > 0.f) ent += c0 * logf(c0);
    if (c1 > 0.f) ent += c1 * logf(c1);
    if (c2 > 0.f) ent += c2 * logf(c2);
    if (c3 > 0.f) ent += c3 * logf(c3);
    ent += __shfl_xor(ent, 1);
    ent += __shfl_xor(ent, 2);
    ent += __shfl_xor(ent, 4);
    if (sg == 0) entc[col] = -ent;
  }
  __syncthreads();

  // ---- Phase D: part[n] = sum over own 4 cols of c*U, then 8-lane fold.
  {
    float part[16];
#pragma unroll
    for (int n = 0; n < 16; ++n) part[n] = 0.f;
#pragma unroll
    for (int k = 0; k < 4; ++k) {
      float c = ct[bca(j, cg + 8 * k)];
#pragma unroll
      for (int q = 0; q < 4; ++q) {
        float4 uu = Ur[k][q];
        part[4 * q + 0] = fmaf(c, uu.x, part[4 * q + 0]);
        part[4 * q + 1] = fmaf(c, uu.y, part[4 * q + 1]);
        part[4 * q + 2] = fmaf(c, uu.z, part[4 * q + 2]);
        part[4 * q + 3] = fmaf(c, uu.w, part[4 * q + 3]);
      }
    }
    // fold-reduce over the 8 lanes (cg) of this j-group, halving values/stage
    float nw[8];
#pragma unroll
    for (int i = 0; i < 8; ++i) {
      float send = (cg & 1) ? part[i] : part[i + 8];
      float recv = __shfl_xor(send, 1);
      nw[i] = ((cg & 1) ? part[i + 8] : part[i]) + recv;
    }
    float n2[4];
#pragma unroll
    for (int i = 0; i < 4; ++i) {
      float send = (cg & 2) ? nw[i] : nw[i + 4];
      float recv = __shfl_xor(send, 2);
      n2[i] = ((cg & 2) ? nw[i + 4] : nw[i]) + recv;
    }
    float n3[2];
#pragma unroll
    for (int i = 0; i < 2; ++i) {
      float send = (cg & 4) ? n2[i] : n2[i + 2];
      float recv = __shfl_xor(send, 4);
      n3[i] = ((cg & 4) ? n2[i + 2] : n2[i]) + recv;
    }
    int base = (cg & 1) * 8 + (cg & 2) * 2 + ((cg & 4) >> 1);
    int outi = (b * NJ + j) * NN + base;
    unsafeAtomicAdd(&s_out[outi], n3[0]);
    unsafeAtomicAdd(&s_out[outi + 1], n3[1]);
  }
  // ---- block entropy flush
  if (t < 32) {
    float e = entc[t];
    e += __shfl_xor(e, 1);
    e += __shfl_xor(e, 2);
    e += __shfl_xor(e, 4);
    e += __shfl_xor(e, 8);
    e += __shfl_xor(e, 16);
    if (t == 0) unsafeAtomicAdd(ent_accum, e);
  }
}

// ---------------------------------------------------------------- launch
extern "C" void kernel_launch(void* const* d_in, const int* in_sizes, int n_in,
                              void* d_out, int out_size, void* d_ws, size_t ws_size,
                              hipStream_t stream) {
  (void)in_sizes; (void)n_in; (void)out_size; (void)ws_size;
  const float* u = (const float*)d_in[0];
  const float* bias = (const float*)d_in[1];
  float* ws = (float*)d_ws;
  // ws layout (floats): [s1 65536][s2 65536][ent 2 + pad 2][s0 65536][v0 65536][v1 65536][kth0 147456]
  float* s1 = ws;
  float* s2 = ws + 65536;
  float* ent = ws + 131072;
  float* s0 = ws + 131076;
  float* v0 = ws + 196612;
  float* v1 = ws + 262148;
  float* kth0 = ws + 327684;
  float* dout = (float*)d_out;

  hipMemsetAsync(d_ws, 0, (size_t)(131072 + 4) * sizeof(float), stream);  // s1,s2,ent

  k_reduce_s0<<<dim3(NB * NJ), dim3(256), 0, stream>>>(u, s0);
  k_squash<<<dim3(256), dim3(256), 0, stream>>>(s0, bias, v0, (const float*)nullptr, 0);
  k_route<1><<<dim3(NB * NTILES), dim3(256), 0, stream>>>(u, v0, v0, kth0, s1, ent + 0);
  k_squash<<<dim3(256), dim3(256), 0, stream>>>(s1, bias, v1, (const float*)nullptr, 0);
  k_route<0><<<dim3(NB * NTILES), dim3(256), 0, stream>>>(u, v1, v0, kth0, s2, ent + 1);
  k_squash<<<dim3(256), dim3(256), 0, stream>>>(s2, bias, dout, ent, 1);
}

// Round 5
// 568.404 us; speedup vs baseline: 1.0212x; 1.0082x over previous
//
#include <hip/hip_runtime.h>
#include <math.h>

// Dynamic routing (capsule nets): B=128, J=32, I=1152, N=16, iters=3, topk=[0.3,0.3]
//
// R5: fused pipeline (5 graph nodes), register-resident U, inline squash,
//     alternating pass direction for Infinity-Cache (L3) reuse.
//   memset(s1,s2,ent)
//   P1: s0[b,j,n] = (1/32) sum_i u          (forward order)
//   P2: route<1,REV=1>: v0=squash(s0) inline; a0=U.v0; rank->kth0->mask;
//       c1 -> ent1, s1 += c1*U              (REVERSED order -> L3 hits)
//   P3: route<0,REV=0>: v1=squash(s1), v0=squash(s0) inline (bit-identical);
//       a1=U.v1; b2=mask(a0)+a1; c2 -> ent2, s2   (forward -> L3 hits)
//   F : d_out = squash(s2+bias), stats[3]
// sparsify at iter1 is a provable no-op (>=9 entries already -inf), so only
// kth0 per column is persisted; P3 recomputes a0 bit-identically from s0.

#define NB 128
#define NJ 32
#define NI 1152
#define NN 16
#define TI 32
#define NTILES (NI / TI)          // 36
#define NBLK (NB * NTILES)        // 4608
#define COLS_TOTAL (NB * NI)      // 147456

// LDS address for (j,col) score/coeff tiles: stride 33 + col rotate by 4j.
__device__ __forceinline__ int bca(int j, int col) {
  return j * 33 + ((col + 4 * j) & 31);
}

// v[j*20+n] (LDS, pad to 20 for conflict-free b128 reads) from s[b*512+j*16+n]
// (+bias, reset). Deterministic op order -> bitwise reproducible across kernels.
__device__ __forceinline__ void inline_squash(const float* __restrict__ s,
                                              const float* __restrict__ bias,
                                              int b, float* vsh, int t) {
#pragma unroll
  for (int p = 0; p < 2; ++p) {
    int idx = p * 256 + t;          // 0..511 = j*16+n
    float sv = s[b * 512 + idx];
    float ssum = sv;
#pragma unroll
    for (int m = 1; m < 16; m <<= 1) ssum += __shfl_xor(ssum, m);
    float sb = sv + bias[idx];
    if (ssum == 0.0f) sb = 0.0f;    // reference reset_mask
    float sq = sb * sb;
#pragma unroll
    for (int m = 1; m < 16; m <<= 1) sq += __shfl_xor(sq, m);
    vsh[(idx >> 4) * 20 + (idx & 15)] = (sq / (1.0f + sq)) * sb / sqrtf(sq);
  }
}

// ---------------------------------------------------------------- P1: s0
__global__ __launch_bounds__(256) void k_reduce_s0(const float* __restrict__ u,
                                                   float* __restrict__ s0) {
  int bj = blockIdx.x;  // b*32 + j
  const float4* u4 = (const float4*)u + (size_t)bj * (NI * NN / 4);  // 4608 float4
  int t = threadIdx.x;
  float4 acc = make_float4(0.f, 0.f, 0.f, 0.f);
#pragma unroll
  for (int k = 0; k < 18; ++k) {
    float4 x = u4[t + 256 * k];
    acc.x += x.x; acc.y += x.y; acc.z += x.z; acc.w += x.w;
  }
#pragma unroll
  for (int m = 4; m <= 32; m <<= 1) {
    acc.x += __shfl_xor(acc.x, m);
    acc.y += __shfl_xor(acc.y, m);
    acc.z += __shfl_xor(acc.z, m);
    acc.w += __shfl_xor(acc.w, m);
  }
  __shared__ float4 parts[4][4];
  int lane = t & 63, w = t >> 6;
  if (lane < 4) parts[w][lane] = acc;
  __syncthreads();
  if (t < 4) {
    float4 p0 = parts[0][t], p1 = parts[1][t], p2 = parts[2][t], p3 = parts[3][t];
    float4 r;
    r.x = (p0.x + p1.x + p2.x + p3.x) * (1.0f / 32.0f);
    r.y = (p0.y + p1.y + p2.y + p3.y) * (1.0f / 32.0f);
    r.z = (p0.z + p1.z + p2.z + p3.z) * (1.0f / 32.0f);
    r.w = (p0.w + p1.w + p2.w + p3.w) * (1.0f / 32.0f);
    ((float4*)(s0 + (size_t)bj * NN))[t] = r;
  }
}

// ---------------------------------------------------------------- final squash
__global__ __launch_bounds__(256) void k_final(const float* __restrict__ s,
                                               const float* __restrict__ bias,
                                               float* __restrict__ vout,
                                               const float* __restrict__ ent) {
  int gid = blockIdx.x * 256 + threadIdx.x;   // [0, 65536)
  int n = gid & 15;
  int j = (gid >> 4) & 31;
  float sv = s[gid];
  float ssum = sv;
#pragma unroll
  for (int m = 1; m < 16; m <<= 1) ssum += __shfl_xor(ssum, m);
  float sb = sv + bias[j * NN + n];
  if (ssum == 0.0f) sb = 0.0f;
  float sq = sb * sb;
#pragma unroll
  for (int m = 1; m < 16; m <<= 1) sq += __shfl_xor(sq, m);
  vout[gid] = (sq / (1.0f + sq)) * sb / sqrtf(sq);
  if (gid < 3) {
    float val = (gid == 0) ? logf(32.0f) : ent[gid - 1] / (float)COLS_TOTAL;
    vout[NB * NJ * NN + gid] = val;
  }
}

// ---------------------------------------------------------------- routing pass
// SPARS=1: P2 (vA=squash(sA), a0=U.vA, rank->kth0->mask, c1, ent, s_out)
// SPARS=0: P3 (vA=squash(sA), vB=squash(sB) bit-identical to P2's vA,
//              a1=U.vA, a0=U.vB, b2=mask(a0)+a1, c2, ent, s_out)
template <int SPARS, int REV>
__global__ __launch_bounds__(256) void k_route(const float* __restrict__ u,
                                               const float* __restrict__ sA,
                                               const float* __restrict__ sB,
                                               const float* __restrict__ bias,
                                               float* __restrict__ kth0,
                                               float* __restrict__ s_out,
                                               float* __restrict__ ent_accum) {
  __shared__ __align__(16) float vAsh[NJ * 20];
  __shared__ __align__(16) float vBsh[NJ * 20];
  __shared__ float bc[32 * 33];   // scores
  __shared__ float ct[32 * 33];   // coeffs
  __shared__ float entc[32];

  int t = threadIdx.x;
  int bid = REV ? (NBLK - 1 - (int)blockIdx.x) : (int)blockIdx.x;
  int b = bid / NTILES;
  int tile = bid - b * NTILES;
  int i0 = tile * TI;
  int j = t >> 3, cg = t & 7;

  // ---- U into registers: Ur[k][q] = u[b,j,i0+cg+8k, 4q..4q+3]  (in flight
  // while inline squashes run below)
  const float4* up = (const float4*)u + ((size_t)(b * NJ + j) * NI + i0 + cg) * 4;
  float4 Ur[4][4];
#pragma unroll
  for (int k = 0; k < 4; ++k)
#pragma unroll
    for (int q = 0; q < 4; ++q) Ur[k][q] = up[k * 32 + q];

  // ---- inline v computation (2KB L2-hot reads)
  inline_squash(sA, bias, b, vAsh, t);
  if (SPARS == 0) inline_squash(sB, bias, b, vBsh, t);

  float kthc[4];
  if (SPARS == 0) {
#pragma unroll
    for (int k = 0; k < 4; ++k) kthc[k] = kth0[b * NI + i0 + cg + 8 * k];
  }
  __syncthreads();

  // ---- Phase B: agreement dots
  float accA[4] = {0.f, 0.f, 0.f, 0.f};
  float accB[4] = {0.f, 0.f, 0.f, 0.f};
#pragma unroll
  for (int q = 0; q < 4; ++q) {
    float4 vaq = *(const float4*)&vAsh[j * 20 + q * 4];
    float4 vbq;
    if (SPARS == 0) vbq = *(const float4*)&vBsh[j * 20 + q * 4];
#pragma unroll
    for (int k = 0; k < 4; ++k) {
      float4 uu = Ur[k][q];
      accA[k] = fmaf(uu.x, vaq.x, accA[k]);
      accA[k] = fmaf(uu.y, vaq.y, accA[k]);
      accA[k] = fmaf(uu.z, vaq.z, accA[k]);
      accA[k] = fmaf(uu.w, vaq.w, accA[k]);
      if (SPARS == 0) {  // same fmaf order as P2's accA -> bit-identical a0
        accB[k] = fmaf(uu.x, vbq.x, accB[k]);
        accB[k] = fmaf(uu.y, vbq.y, accB[k]);
        accB[k] = fmaf(uu.z, vbq.z, accB[k]);
        accB[k] = fmaf(uu.w, vbq.w, accB[k]);
      }
    }
  }
#pragma unroll
  for (int k = 0; k < 4; ++k) {
    float bv;
    if (SPARS)
      bv = accA[k];  // b1_pre = 0 + a0
    else
      bv = ((accB[k] <= kthc[k]) ? -INFINITY : accB[k]) + accA[k];  // b2
    bc[bca(j, cg + 8 * k)] = bv;
  }
  __syncthreads();

  // ---- Phase S: per column (8 lanes/col): [rank->kth->mask], softmax, entropy
  {
    int col = t >> 3, sg = t & 7;
    float own0 = bc[bca(sg * 4 + 0, col)];
    float own1 = bc[bca(sg * 4 + 1, col)];
    float own2 = bc[bca(sg * 4 + 2, col)];
    float own3 = bc[bca(sg * 4 + 3, col)];
    float m;
    if (SPARS) {
      int r0 = 0, r1 = 0, r2 = 0, r3 = 0, e0 = 0, e1 = 0, e2 = 0, e3 = 0;
      m = -INFINITY;
#pragma unroll
      for (int jj = 0; jj < 32; ++jj) {
        float bj = bc[bca(jj, col)];  // 8-lane broadcast
        m = fmaxf(m, bj);
        r0 += (bj < own0); e0 += (bj == own0);
        r1 += (bj < own1); e1 += (bj == own1);
        r2 += (bj < own2); e2 += (bj == own2);
        r3 += (bj < own3); e3 += (bj == own3);
      }
      // kth smallest (sorted index 8 == mask_count-1): r<=8 < r+eq
      float cand = -INFINITY;
      if (r0 <= 8 && 8 < r0 + e0) cand = fmaxf(cand, own0);
      if (r1 <= 8 && 8 < r1 + e1) cand = fmaxf(cand, own1);
      if (r2 <= 8 && 8 < r2 + e2) cand = fmaxf(cand, own2);
      if (r3 <= 8 && 8 < r3 + e3) cand = fmaxf(cand, own3);
      cand = fmaxf(cand, __shfl_xor(cand, 1));
      cand = fmaxf(cand, __shfl_xor(cand, 2));
      cand = fmaxf(cand, __shfl_xor(cand, 4));
      if (own0 <= cand) own0 = -INFINITY;
      if (own1 <= cand) own1 = -INFINITY;
      if (own2 <= cand) own2 = -INFINITY;
      if (own3 <= cand) own3 = -INFINITY;
      if (sg == 0) kth0[b * NI + i0 + col] = cand;
      // pre-mask max == post-mask max: the max always survives masking
    } else {
      float lm = fmaxf(fmaxf(own0, own1), fmaxf(own2, own3));
      lm = fmaxf(lm, __shfl_xor(lm, 1));
      lm = fmaxf(lm, __shfl_xor(lm, 2));
      lm = fmaxf(lm, __shfl_xor(lm, 4));
      m = lm;
    }
    float x0 = expf(own0 - m), x1 = expf(own1 - m);
    float x2 = expf(own2 - m), x3 = expf(own3 - m);
    float ps = (x0 + x1) + (x2 + x3);
    ps += __shfl_xor(ps, 1);
    ps += __shfl_xor(ps, 2);
    ps += __shfl_xor(ps, 4);
    float c0 = x0 / ps, c1 = x1 / ps, c2 = x2 / ps, c3 = x3 / ps;
    ct[bca(sg * 4 + 0, col)] = c0;
    ct[bca(sg * 4 + 1, col)] = c1;
    ct[bca(sg * 4 + 2, col)] = c2;
    ct[bca(sg * 4 + 3, col)] = c3;
    float ent = 0.f;
    if (c0 > 0.f) ent += c0 * logf(c0);
    if (c1 > 0.f) ent += c1 * logf(c1);
    if (c2 > 0.f) ent += c2 * logf(c2);
    if (c3 > 0.f) ent += c3 * logf(c3);
    ent += __shfl_xor(ent, 1);
    ent += __shfl_xor(ent, 2);
    ent += __shfl_xor(ent, 4);
    if (sg == 0) entc[col] = -ent;
  }
  __syncthreads();

  // ---- Phase D: part[n] = sum over own 4 cols of c*U, then 8-lane fold.
  {
    float part[16];
#pragma unroll
    for (int n = 0; n < 16; ++n) part[n] = 0.f;
#pragma unroll
    for (int k = 0; k < 4; ++k) {
      float c = ct[bca(j, cg + 8 * k)];
#pragma unroll
      for (int q = 0; q < 4; ++q) {
        float4 uu = Ur[k][q];
        part[4 * q + 0] = fmaf(c, uu.x, part[4 * q + 0]);
        part[4 * q + 1] = fmaf(c, uu.y, part[4 * q + 1]);
        part[4 * q + 2] = fmaf(c, uu.z, part[4 * q + 2]);
        part[4 * q + 3] = fmaf(c, uu.w, part[4 * q + 3]);
      }
    }
    // fold-reduce over the 8 lanes (cg) of this j-group
    float nw[8];
#pragma unroll
    for (int i = 0; i < 8; ++i) {
      float send = (cg & 1) ? part[i] : part[i + 8];
      float recv = __shfl_xor(send, 1);
      nw[i] = ((cg & 1) ? part[i + 8] : part[i]) + recv;
    }
    float n2[4];
#pragma unroll
    for (int i = 0; i < 4; ++i) {
      float send = (cg & 2) ? nw[i] : nw[i + 4];
      float recv = __shfl_xor(send, 2);
      n2[i] = ((cg & 2) ? nw[i + 4] : nw[i]) + recv;
    }
    float n3[2];
#pragma unroll
    for (int i = 0; i < 2; ++i) {
      float send = (cg & 4) ? n2[i] : n2[i + 2];
      float recv = __shfl_xor(send, 4);
      n3[i] = ((cg & 4) ? n2[i + 2] : n2[i]) + recv;
    }
    int base = (cg & 1) * 8 + (cg & 2) * 2 + ((cg & 4) >> 1);
    int outi = (b * NJ + j) * NN + base;
    unsafeAtomicAdd(&s_out[outi], n3[0]);
    unsafeAtomicAdd(&s_out[outi + 1], n3[1]);
  }
  // ---- block entropy flush
  if (t < 32) {
    float e = entc[t];
    e += __shfl_xor(e, 1);
    e += __shfl_xor(e, 2);
    e += __shfl_xor(e, 4);
    e += __shfl_xor(e, 8);
    e += __shfl_xor(e, 16);
    if (t == 0) unsafeAtomicAdd(ent_accum, e);
  }
}

// ---------------------------------------------------------------- launch
extern "C" void kernel_launch(void* const* d_in, const int* in_sizes, int n_in,
                              void* d_out, int out_size, void* d_ws, size_t ws_size,
                              hipStream_t stream) {
  (void)in_sizes; (void)n_in; (void)out_size; (void)ws_size;
  const float* u = (const float*)d_in[0];
  const float* bias = (const float*)d_in[1];
  float* ws = (float*)d_ws;
  // ws floats: [s1 65536][s2 65536][ent 2 + pad 2][s0 65536][kth0 147456]
  float* s1 = ws;
  float* s2 = ws + 65536;
  float* ent = ws + 131072;
  float* s0 = ws + 131076;
  float* kth0 = ws + 196612;
  float* dout = (float*)d_out;

  hipMemsetAsync(d_ws, 0, (size_t)(131072 + 4) * sizeof(float), stream);  // s1,s2,ent

  k_reduce_s0<<<dim3(NB * NJ), dim3(256), 0, stream>>>(u, s0);
  k_route<1, 1><<<dim3(NBLK), dim3(256), 0, stream>>>(u, s0, s0, bias, kth0, s1, ent + 0);
  k_route<0, 0><<<dim3(NBLK), dim3(256), 0, stream>>>(u, s1, s0, bias, kth0, s2, ent + 1);
  k_final<<<dim3(256), dim3(256), 0, stream>>>(s2, bias, dout, ent);
}